// Round 8
// baseline (227.079 us; speedup 1.0000x reference)
//
#include <hip/hip_runtime.h>
#include <math.h>

// Problem constants (from reference setup_inputs)
#define BBATCH 16
#define NPTS   4096
#define MPTS   1024
#define C1c    128
#define C2c    256
#define CINc   384
#define H1c    256
#define H2c    128
#define TN     64

typedef _Float16 f16x8 __attribute__((ext_vector_type(8)));
typedef _Float16 f16x4 __attribute__((ext_vector_type(4)));
typedef float    f32x4 __attribute__((ext_vector_type(4)));

#define LDI  40    // f16 stride, s_inv rows [64 n][32 m]
#define LDXc 408   // f16 stride, s_X rows (fused fallback)
#define LDH  264   // f16 stride, s_H rows [64 n][256 k]

// ---- fragment-swizzled workspace layout (f16 elements) ----
//   p2s: frag ((b*32+s)*16 + wt)*64 + lane : (c=wt*16+(lane&15), m=s*32+(lane>>4)*8+i)
//   W1s: frag (wt*12 + kc)*64 + lane       : (o=wt*16+(lane&15), k=kc*32+(lane>>4)*8+i)
//   W2s: frag (wt2*8 + oc)*64 + lane       : (o=wt2*16+(lane&15), k=oc*32+(lane>>4)*8+i)
//   xs : frag (((b*64+ntile)*4 + nt)*12 + kc)*64 + lane
//        : (k=kc*32+(lane>>4)*8+j, n=ntile*64+nt*16+(lane&15)); k<128 = p1, k>=128 = interp
#define NFRAG_P2  (BBATCH * 32 * 16 * 64)        // 524288
#define NFRAG_W1  (16 * 12 * 64)                 // 12288
#define NFRAG_W2  (8 * 8 * 64)                   // 4096
#define NFRAG_XS  (BBATCH * 64 * 4 * 12 * 64)    // 3145728
#define WS_P2S  0
#define WS_W1S  (NFRAG_P2 * 8)                   // 4194304
#define WS_W2S  (WS_W1S + NFRAG_W1 * 8)
#define WS_XS   (WS_W2S + NFRAG_W2 * 8)          // 4325376
#define WS_F16_FUSED  WS_XS                      // fused fallback needs this many f16
#define WS_F16_SPLIT  (WS_XS + (size_t)NFRAG_XS * 8)   // 29491200 f16 = 59 MB

// ---------------------------------------------------------------------------
// pre-pass 1: convert + swizzle p2 / W1 / W2 into fragment-contiguous f16
__global__ __launch_bounds__(256) void cvt_swz(
    const float* __restrict__ p2, const float* __restrict__ W1,
    const float* __restrict__ W2, _Float16* __restrict__ ws)
{
    const int t = blockIdx.x * 256 + threadIdx.x;   // one fragment (8 f16) per thread
    const float* src;
    _Float16* dst;
    if (t < NFRAG_P2) {
        const int lane = t & 63, wt = (t >> 6) & 15, s = (t >> 10) & 31, b = t >> 15;
        const int c = wt * 16 + (lane & 15);
        const int m = s * 32 + (lane >> 4) * 8;
        src = p2 + ((size_t)(b * C2c + c)) * MPTS + m;
        dst = ws + WS_P2S + (size_t)t * 8;
    } else if (t < NFRAG_P2 + NFRAG_W1) {
        const int u = t - NFRAG_P2;
        const int lane = u & 63, kc = (u >> 6) % 12, wt = (u >> 6) / 12;
        const int o = wt * 16 + (lane & 15);
        const int k = kc * 32 + (lane >> 4) * 8;
        src = W1 + (size_t)o * CINc + k;
        dst = ws + WS_W1S + (size_t)u * 8;
    } else {
        const int v = t - NFRAG_P2 - NFRAG_W1;
        const int lane = v & 63, oc = (v >> 6) & 7, wt2 = v >> 9;
        const int o = wt2 * 16 + (lane & 15);
        const int k = oc * 32 + (lane >> 4) * 8;
        src = W2 + (size_t)o * H1c + k;
        dst = ws + WS_W2S + (size_t)v * 8;
    }
    const float4 a0 = *(const float4*)(src);
    const float4 a1 = *(const float4*)(src + 4);
    f16x8 h;
    h[0] = (_Float16)a0.x; h[1] = (_Float16)a0.y; h[2] = (_Float16)a0.z; h[3] = (_Float16)a0.w;
    h[4] = (_Float16)a1.x; h[5] = (_Float16)a1.y; h[6] = (_Float16)a1.z; h[7] = (_Float16)a1.w;
    *(f16x8*)dst = h;
}

// ---------------------------------------------------------------------------
// pre-pass 2: p1 -> xs frags for k in [0,128). Coalesced f32 reads along n;
// 8 x 2B frag stores (stride 16B) per thread.
__global__ __launch_bounds__(256) void cvt_p1(
    const float* __restrict__ p1, _Float16* __restrict__ xs)
{
    const int t  = blockIdx.x * 256 + threadIdx.x;   // 1,048,576 threads
    const int n0 = (t & 511) * 8;
    const int k  = (t >> 9) & 127;
    const int b  = t >> 16;
    const float* src = p1 + ((size_t)(b * C1c + k)) * NPTS + n0;
    const float4 a0 = *(const float4*)(src);
    const float4 a1 = *(const float4*)(src + 4);
    float v[8] = {a0.x, a0.y, a0.z, a0.w, a1.x, a1.y, a1.z, a1.w};
    const int kc = k >> 5, khi = (k >> 3) & 3, j = k & 7;
    #pragma unroll
    for (int i = 0; i < 8; ++i) {
        const int n = n0 + i;
        const int ntile = n >> 6, nt = (n >> 4) & 3;
        const int lane = (n & 15) + khi * 16;
        xs[((((size_t)(b * 64 + ntile) * 4 + nt) * 12 + kc) * 64 + lane) * 8 + j] = (_Float16)v[i];
    }
}

// ---------------------------------------------------------------------------
// Kernel 1: interp only. Phase A of R7 (A = p2s frags contiguous from L2,
// B = inv chunk in LDS dbuf, 1 barrier/step) but with tiny LDS (11.5 KB) so
// occupancy is grid-limited, and an epilogue that writes normalized interp
// straight into xs B-frag layout (k in [128,384)).
__global__ __launch_bounds__(256, 3) void interp_k(
    const float* __restrict__ xyz1, const float* __restrict__ xyz2,
    const _Float16* __restrict__ p2s, _Float16* __restrict__ xs)
{
    __shared__ __align__(16) char smem[11520];
    _Float16* s_inv   = (_Float16*)(smem);          // 10240 B dbuf
    float*    s_red   = (float*)(smem + 10240);     // 1024 B
    float*    s_recip = (float*)(smem + 11264);     // 256 B

    const int tid  = threadIdx.x;
    const int w    = tid >> 6;    // wave 0..3: owns c-rows [w*64, +64)
    const int L    = tid & 63;
    const int quad = L >> 4;
    const int l16  = L & 15;

    const int id    = blockIdx.x;
    const int b     = (id & 7) * 2 + ((id >> 3) & 1);
    const int ntile = id >> 4;
    const int n0    = ntile * TN;

    const float* __restrict__ z2b = xyz2 + (size_t)b * MPTS * 3;
    const _Float16* __restrict__ p2sb =
        p2s + (((size_t)b * 32 * 16 + (size_t)w * 4) * 64 + L) * 8;

    const float x1x = xyz1[((size_t)b * NPTS + n0 + L) * 3 + 0];
    const float x1y = xyz1[((size_t)b * NPTS + n0 + L) * 3 + 1];
    const float x1z = xyz1[((size_t)b * NPTS + n0 + L) * 3 + 2];

    f32x4 acc[4][4];
    #pragma unroll
    for (int ct = 0; ct < 4; ++ct)
        #pragma unroll
        for (int nt = 0; nt < 4; ++nt)
            acc[ct][nt] = (f32x4){0.f, 0.f, 0.f, 0.f};

    float ssum = 0.f;
    f16x8 Aa[2][4];

    auto loadA = [&](int s, f16x8 dst[4]) {
        const _Float16* ap = p2sb + (size_t)s * (16 * 64 * 8);
        #pragma unroll
        for (int ct = 0; ct < 4; ++ct)
            dst[ct] = *(const f16x8*)(ap + (size_t)ct * (64 * 8));
    };

    auto gen = [&](int s) {
        const float* zp = z2b + (size_t)(s * 32 + w * 8) * 3;   // wave-uniform
        f32x4 zr[6];
        #pragma unroll
        for (int j = 0; j < 6; ++j) zr[j] = ((const f32x4*)zp)[j];
        const float* zv = (const float*)zr;
        f16x8 iv;
        #pragma unroll
        for (int i = 0; i < 8; ++i) {
            const float dx = x1x - zv[3 * i + 0];
            const float dy = x1y - zv[3 * i + 1];
            const float dz = x1z - zv[3 * i + 2];
            const float d2 = fmaf(dx, dx, fmaf(dy, dy, fmaf(dz, dz, 1e-12f)));
            const float inv = __builtin_amdgcn_rsqf(d2);
            ssum += inv;
            iv[i] = (_Float16)inv;
        }
        *(f16x8*)(s_inv + (s & 1) * (64 * LDI) + L * LDI + w * 8) = iv;
    };

    loadA(0, Aa[0]);
    gen(0);
    __syncthreads();

    #pragma unroll 2
    for (int s = 0; s < 32; ++s) {
        const int cur = s & 1;
        if (s + 1 < 32) {
            loadA(s + 1, Aa[cur ^ 1]);
            gen(s + 1);
        }
        const _Float16* bb = s_inv + cur * (64 * LDI) + l16 * LDI + quad * 8;
        #pragma unroll
        for (int nt = 0; nt < 4; ++nt) {
            const f16x8 bf = *(const f16x8*)(bb + nt * (16 * LDI));
            #pragma unroll
            for (int ct = 0; ct < 4; ++ct)
                acc[ct][nt] = __builtin_amdgcn_mfma_f32_16x16x32_f16(Aa[cur][ct], bf, acc[ct][nt], 0, 0, 0);
        }
        __syncthreads();
    }

    // S[n] reduction
    s_red[tid] = ssum;
    __syncthreads();
    if (tid < 64)
        s_recip[tid] = 1.0f / (s_red[tid] + s_red[tid + 64] + s_red[tid + 128] + s_red[tid + 192]);
    __syncthreads();

    // epilogue: normalize + write xs frags (k = 128 + c)
    {
        float rn4[4];
        #pragma unroll
        for (int nt = 0; nt < 4; ++nt) rn4[nt] = s_recip[nt * 16 + l16];
        _Float16* xb = xs + ((size_t)(b * 64 + ntile) * 4) * (12 * 64 * 8);
        #pragma unroll
        for (int ct = 0; ct < 4; ++ct) {
            const int k   = 128 + w * 64 + ct * 16 + quad * 4;
            const int kc  = k >> 5;
            const int kin = k & 31;
            const int lw  = l16 + ((kin >> 3) & 3) * 16;
            const int j   = kin & 7;   // 0 or 4
            #pragma unroll
            for (int nt = 0; nt < 4; ++nt) {
                const f32x4 v = acc[ct][nt];
                const float r = rn4[nt];
                f16x4 hv;
                hv[0] = (_Float16)(v[0] * r);
                hv[1] = (_Float16)(v[1] * r);
                hv[2] = (_Float16)(v[2] * r);
                hv[3] = (_Float16)(v[3] * r);
                *(f16x4*)(xb + (((size_t)nt * 12 + kc) * 64 + lw) * 8 + j) = hv;
            }
        }
    }
}

// ---------------------------------------------------------------------------
// Kernel 2: MLP only. B-operands stream as contiguous frags from global
// (xs is L2-hot — written by the same-XCD interp block). LDS = s_H only.
__global__ __launch_bounds__(256, 3) void mlp_k(
    const _Float16* __restrict__ W1s, const float* __restrict__ b1v,
    const _Float16* __restrict__ W2s, const float* __restrict__ b2v,
    const _Float16* __restrict__ xs,  float* __restrict__ out)
{
    __shared__ __align__(16) _Float16 s_H[64 * LDH];   // 33792 B

    const int tid  = threadIdx.x;
    const int w    = tid >> 6;
    const int L    = tid & 63;
    const int quad = L >> 4;
    const int l16  = L & 15;

    const int id    = blockIdx.x;
    const int b     = (id & 7) * 2 + ((id >> 3) & 1);
    const int ntile = id >> 4;
    const int n0    = ntile * TN;

    const _Float16* __restrict__ xb = xs + ((size_t)(b * 64 + ntile) * 4) * (12 * 64 * 8);

    // ---------------- Phase B: h = relu(W1 @ x + b1), K=384 ----------------
    f32x4 hacc[4][4];
    #pragma unroll
    for (int ct = 0; ct < 4; ++ct)
        #pragma unroll
        for (int nt = 0; nt < 4; ++nt)
            hacc[ct][nt] = (f32x4){0.f, 0.f, 0.f, 0.f};

    const _Float16* w1b = W1s + (((size_t)(w * 4)) * 12 * 64 + L) * 8;
    #pragma unroll 2
    for (int kc = 0; kc < 12; ++kc) {
        f16x8 af[4], bf[4];
        #pragma unroll
        for (int ct = 0; ct < 4; ++ct)
            af[ct] = *(const f16x8*)(w1b + ((size_t)ct * 12 + kc) * (64 * 8));
        #pragma unroll
        for (int nt = 0; nt < 4; ++nt)
            bf[nt] = *(const f16x8*)(xb + (((size_t)nt * 12 + kc) * 64 + L) * 8);
        #pragma unroll
        for (int nt = 0; nt < 4; ++nt)
            #pragma unroll
            for (int ct = 0; ct < 4; ++ct)
                hacc[ct][nt] = __builtin_amdgcn_mfma_f32_16x16x32_f16(af[ct], bf[nt], hacc[ct][nt], 0, 0, 0);
    }

    // bias + relu + stage h -> s_H[n][o1]
    {
        f32x4 bb[4];
        #pragma unroll
        for (int ct = 0; ct < 4; ++ct)
            bb[ct] = *(const f32x4*)(b1v + w * 64 + ct * 16 + quad * 4);
        #pragma unroll
        for (int ct = 0; ct < 4; ++ct)
            #pragma unroll
            for (int nt = 0; nt < 4; ++nt) {
                const f32x4 v = hacc[ct][nt];
                f16x4 hv;
                hv[0] = (_Float16)fmaxf(v[0] + bb[ct][0], 0.f);
                hv[1] = (_Float16)fmaxf(v[1] + bb[ct][1], 0.f);
                hv[2] = (_Float16)fmaxf(v[2] + bb[ct][2], 0.f);
                hv[3] = (_Float16)fmaxf(v[3] + bb[ct][3], 0.f);
                *(f16x4*)(&s_H[(nt * 16 + l16) * LDH + w * 64 + ct * 16 + quad * 4]) = hv;
            }
    }
    __syncthreads();

    // ---------------- Phase C: out = relu(W2 @ h + b2), K=256 ----------------
    f32x4 oacc[2][4];
    #pragma unroll
    for (int ct = 0; ct < 2; ++ct)
        #pragma unroll
        for (int nt = 0; nt < 4; ++nt)
            oacc[ct][nt] = (f32x4){0.f, 0.f, 0.f, 0.f};

    const _Float16* w2b = W2s + (((size_t)(w * 2)) * 8 * 64 + L) * 8;
    #pragma unroll 2
    for (int oc = 0; oc < 8; ++oc) {
        f16x8 af2[2];
        #pragma unroll
        for (int ct = 0; ct < 2; ++ct)
            af2[ct] = *(const f16x8*)(w2b + ((size_t)ct * 8 + oc) * (64 * 8));
        #pragma unroll
        for (int nt = 0; nt < 4; ++nt) {
            const f16x8 bf = *(const f16x8*)(&s_H[(nt * 16 + l16) * LDH + oc * 32 + quad * 8]);
            #pragma unroll
            for (int ct = 0; ct < 2; ++ct)
                oacc[ct][nt] = __builtin_amdgcn_mfma_f32_16x16x32_f16(af2[ct], bf, oacc[ct][nt], 0, 0, 0);
        }
    }

    // epilogue: bias + relu + store
    {
        f32x4 bb2[2];
        #pragma unroll
        for (int ct = 0; ct < 2; ++ct)
            bb2[ct] = *(const f32x4*)(b2v + w * 32 + ct * 16 + quad * 4);
        #pragma unroll
        for (int ct = 0; ct < 2; ++ct)
            #pragma unroll
            for (int nt = 0; nt < 4; ++nt) {
                float* op = out + ((size_t)b * H2c + w * 32 + ct * 16 + quad * 4) * NPTS
                                + n0 + nt * 16 + l16;
                #pragma unroll
                for (int j = 0; j < 4; ++j)
                    op[(size_t)j * NPTS] = fmaxf(oacc[ct][nt][j] + bb2[ct][j], 0.f);
            }
    }
}

// ---------------------------------------------------------------------------
// Fused fallback (R7 kernel, f16-swizzled or f32 paths) for small ws_size.
#define OFF_INV   0
#define OFF_RED   10240
#define OFF_RECIP 52224
#define SMEM_BYTES 52480

template <bool F16P>
__global__ __launch_bounds__(256, 3) void fp_mfma6(
    const float* __restrict__ xyz1, const float* __restrict__ xyz2,
    const float* __restrict__ p1,   const float* __restrict__ p2,
    const float* __restrict__ W1,   const float* __restrict__ b1v,
    const float* __restrict__ W2,   const float* __restrict__ b2v,
    const _Float16* __restrict__ p2s, const _Float16* __restrict__ W1s,
    const _Float16* __restrict__ W2s,
    float* __restrict__ out)
{
    __shared__ __align__(16) char smem[SMEM_BYTES];
    _Float16* s_inv   = (_Float16*)(smem + OFF_INV);
    float*    s_red   = (float*)(smem + OFF_RED);
    float*    s_recip = (float*)(smem + OFF_RECIP);
    _Float16* s_X     = (_Float16*)smem;
    _Float16* s_H     = (_Float16*)smem;

    const int tid  = threadIdx.x;
    const int w    = tid >> 6;
    const int L    = tid & 63;
    const int quad = L >> 4;
    const int l16  = L & 15;

    const int id = blockIdx.x;
    const int b  = (id & 7) * 2 + ((id >> 3) & 1);
    const int n0 = (id >> 4) * TN;

    const float* __restrict__ z2b = xyz2 + (size_t)b * MPTS * 3;
    const float* __restrict__ p2b = p2   + (size_t)b * C2c * MPTS;
    const _Float16* __restrict__ p2sb =
        F16P ? (p2s + (((size_t)b * 32 * 16 + (size_t)w * 4) * 64 + L) * 8) : (const _Float16*)nullptr;

    const float x1x = xyz1[((size_t)b * NPTS + n0 + L) * 3 + 0];
    const float x1y = xyz1[((size_t)b * NPTS + n0 + L) * 3 + 1];
    const float x1z = xyz1[((size_t)b * NPTS + n0 + L) * 3 + 2];

    f32x4 acc[4][4];
    #pragma unroll
    for (int ct = 0; ct < 4; ++ct)
        #pragma unroll
        for (int nt = 0; nt < 4; ++nt)
            acc[ct][nt] = (f32x4){0.f, 0.f, 0.f, 0.f};

    float ssum = 0.f;
    f16x8 Aa[2][4];

    auto loadA = [&](int s, f16x8 dst[4]) {
        if (F16P) {
            const _Float16* ap = p2sb + (size_t)s * (16 * 64 * 8);
            #pragma unroll
            for (int ct = 0; ct < 4; ++ct)
                dst[ct] = *(const f16x8*)(ap + (size_t)ct * (64 * 8));
        } else {
            const float* ap = p2b + (size_t)(w * 64 + l16) * MPTS + s * 32 + quad * 8;
            #pragma unroll
            for (int ct = 0; ct < 4; ++ct) {
                const float4 a0 = *(const float4*)(ap + (size_t)ct * (16 * MPTS));
                const float4 a1 = *(const float4*)(ap + (size_t)ct * (16 * MPTS) + 4);
                f16x8 h;
                h[0] = (_Float16)a0.x; h[1] = (_Float16)a0.y; h[2] = (_Float16)a0.z; h[3] = (_Float16)a0.w;
                h[4] = (_Float16)a1.x; h[5] = (_Float16)a1.y; h[6] = (_Float16)a1.z; h[7] = (_Float16)a1.w;
                dst[ct] = h;
            }
        }
    };

    auto gen = [&](int s) {
        const float* zp = z2b + (size_t)(s * 32 + w * 8) * 3;
        f32x4 zr[6];
        #pragma unroll
        for (int j = 0; j < 6; ++j) zr[j] = ((const f32x4*)zp)[j];
        const float* zv = (const float*)zr;
        f16x8 iv;
        #pragma unroll
        for (int i = 0; i < 8; ++i) {
            const float dx = x1x - zv[3 * i + 0];
            const float dy = x1y - zv[3 * i + 1];
            const float dz = x1z - zv[3 * i + 2];
            const float d2 = fmaf(dx, dx, fmaf(dy, dy, fmaf(dz, dz, 1e-12f)));
            const float inv = __builtin_amdgcn_rsqf(d2);
            ssum += inv;
            iv[i] = (_Float16)inv;
        }
        *(f16x8*)(s_inv + (s & 1) * (64 * LDI) + L * LDI + w * 8) = iv;
    };

    loadA(0, Aa[0]);
    gen(0);
    __syncthreads();

    #pragma unroll 2
    for (int s = 0; s < 32; ++s) {
        const int cur = s & 1;
        if (s + 1 < 32) {
            loadA(s + 1, Aa[cur ^ 1]);
            gen(s + 1);
        }
        const _Float16* bb = s_inv + cur * (64 * LDI) + l16 * LDI + quad * 8;
        #pragma unroll
        for (int nt = 0; nt < 4; ++nt) {
            const f16x8 bf = *(const f16x8*)(bb + nt * (16 * LDI));
            #pragma unroll
            for (int ct = 0; ct < 4; ++ct)
                acc[ct][nt] = __builtin_amdgcn_mfma_f32_16x16x32_f16(Aa[cur][ct], bf, acc[ct][nt], 0, 0, 0);
        }
        __syncthreads();
    }

    s_red[tid] = ssum;
    __syncthreads();
    if (tid < 64)
        s_recip[tid] = 1.0f / (s_red[tid] + s_red[tid + 64] + s_red[tid + 128] + s_red[tid + 192]);
    __syncthreads();

    {
        float rn4[4];
        #pragma unroll
        for (int nt = 0; nt < 4; ++nt) rn4[nt] = s_recip[nt * 16 + l16];
        #pragma unroll
        for (int ct = 0; ct < 4; ++ct)
            #pragma unroll
            for (int nt = 0; nt < 4; ++nt) {
                const f32x4 v = acc[ct][nt];
                const float r = rn4[nt];
                f16x4 hv;
                hv[0] = (_Float16)(v[0] * r);
                hv[1] = (_Float16)(v[1] * r);
                hv[2] = (_Float16)(v[2] * r);
                hv[3] = (_Float16)(v[3] * r);
                *(f16x4*)(&s_X[(nt * 16 + l16) * LDXc + 128 + w * 64 + ct * 16 + quad * 4]) = hv;
            }
    }
    {
        const float* p1b = p1 + (size_t)b * C1c * NPTS + n0;
        #pragma unroll
        for (int cc = 0; cc < 8; ++cc) {
            const int c = w * 32 + cc * 4;
            f16x4 v;
            v[0] = (_Float16)p1b[(size_t)(c + 0) * NPTS + L];
            v[1] = (_Float16)p1b[(size_t)(c + 1) * NPTS + L];
            v[2] = (_Float16)p1b[(size_t)(c + 2) * NPTS + L];
            v[3] = (_Float16)p1b[(size_t)(c + 3) * NPTS + L];
            *(f16x4*)(&s_X[L * LDXc + c]) = v;
        }
    }
    __syncthreads();

    f32x4 hacc[4][4];
    #pragma unroll
    for (int ct = 0; ct < 4; ++ct)
        #pragma unroll
        for (int nt = 0; nt < 4; ++nt)
            hacc[ct][nt] = (f32x4){0.f, 0.f, 0.f, 0.f};

    #pragma unroll 2
    for (int kc = 0; kc < 12; ++kc) {
        f16x8 af[4];
        if (F16P) {
            const _Float16* wp = W1s + (((size_t)(w * 4) * 12 + kc) * 64 + L) * 8;
            #pragma unroll
            for (int ct = 0; ct < 4; ++ct)
                af[ct] = *(const f16x8*)(wp + (size_t)ct * (12 * 64 * 8));
        } else {
            const float* wp = W1 + (size_t)(w * 64 + l16) * CINc + kc * 32 + quad * 8;
            #pragma unroll
            for (int ct = 0; ct < 4; ++ct) {
                const float4 a0 = *(const float4*)(wp + ct * (16 * CINc));
                const float4 a1 = *(const float4*)(wp + ct * (16 * CINc) + 4);
                f16x8 h;
                h[0] = (_Float16)a0.x; h[1] = (_Float16)a0.y; h[2] = (_Float16)a0.z; h[3] = (_Float16)a0.w;
                h[4] = (_Float16)a1.x; h[5] = (_Float16)a1.y; h[6] = (_Float16)a1.z; h[7] = (_Float16)a1.w;
                af[ct] = h;
            }
        }
        #pragma unroll
        for (int nt = 0; nt < 4; ++nt) {
            const f16x8 bf = *(const f16x8*)(&s_X[(nt * 16 + l16) * LDXc + kc * 32 + quad * 8]);
            #pragma unroll
            for (int ct = 0; ct < 4; ++ct)
                hacc[ct][nt] = __builtin_amdgcn_mfma_f32_16x16x32_f16(af[ct], bf, hacc[ct][nt], 0, 0, 0);
        }
    }

    __syncthreads();

    {
        f32x4 bb[4];
        #pragma unroll
        for (int ct = 0; ct < 4; ++ct)
            bb[ct] = *(const f32x4*)(b1v + w * 64 + ct * 16 + quad * 4);
        #pragma unroll
        for (int ct = 0; ct < 4; ++ct)
            #pragma unroll
            for (int nt = 0; nt < 4; ++nt) {
                const f32x4 v = hacc[ct][nt];
                f16x4 hv;
                hv[0] = (_Float16)fmaxf(v[0] + bb[ct][0], 0.f);
                hv[1] = (_Float16)fmaxf(v[1] + bb[ct][1], 0.f);
                hv[2] = (_Float16)fmaxf(v[2] + bb[ct][2], 0.f);
                hv[3] = (_Float16)fmaxf(v[3] + bb[ct][3], 0.f);
                *(f16x4*)(&s_H[(nt * 16 + l16) * LDH + w * 64 + ct * 16 + quad * 4]) = hv;
            }
    }
    __syncthreads();

    f32x4 oacc[2][4];
    #pragma unroll
    for (int ct = 0; ct < 2; ++ct)
        #pragma unroll
        for (int nt = 0; nt < 4; ++nt)
            oacc[ct][nt] = (f32x4){0.f, 0.f, 0.f, 0.f};

    #pragma unroll 2
    for (int oc = 0; oc < 8; ++oc) {
        f16x8 af2[2];
        if (F16P) {
            const _Float16* wp = W2s + (((size_t)(w * 2) * 8 + oc) * 64 + L) * 8;
            #pragma unroll
            for (int ct = 0; ct < 2; ++ct)
                af2[ct] = *(const f16x8*)(wp + (size_t)ct * (8 * 64 * 8));
        } else {
            const float* wp = W2 + (size_t)(w * 32 + l16) * H1c + oc * 32 + quad * 8;
            #pragma unroll
            for (int ct = 0; ct < 2; ++ct) {
                const float4 a0 = *(const float4*)(wp + ct * (16 * H1c));
                const float4 a1 = *(const float4*)(wp + ct * (16 * H1c) + 4);
                f16x8 h;
                h[0] = (_Float16)a0.x; h[1] = (_Float16)a0.y; h[2] = (_Float16)a0.z; h[3] = (_Float16)a0.w;
                h[4] = (_Float16)a1.x; h[5] = (_Float16)a1.y; h[6] = (_Float16)a1.z; h[7] = (_Float16)a1.w;
                af2[ct] = h;
            }
        }
        #pragma unroll
        for (int nt = 0; nt < 4; ++nt) {
            const f16x8 bf = *(const f16x8*)(&s_H[(nt * 16 + l16) * LDH + oc * 32 + quad * 8]);
            #pragma unroll
            for (int ct = 0; ct < 2; ++ct)
                oacc[ct][nt] = __builtin_amdgcn_mfma_f32_16x16x32_f16(af2[ct], bf, oacc[ct][nt], 0, 0, 0);
        }
    }

    {
        f32x4 bb2[2];
        #pragma unroll
        for (int ct = 0; ct < 2; ++ct)
            bb2[ct] = *(const f32x4*)(b2v + w * 32 + ct * 16 + quad * 4);
        #pragma unroll
        for (int ct = 0; ct < 2; ++ct)
            #pragma unroll
            for (int nt = 0; nt < 4; ++nt) {
                float* op = out + ((size_t)b * H2c + w * 32 + ct * 16 + quad * 4) * NPTS
                                + n0 + nt * 16 + l16;
                #pragma unroll
                for (int j = 0; j < 4; ++j)
                    op[(size_t)j * NPTS] = fmaxf(oacc[ct][nt][j] + bb2[ct][j], 0.f);
            }
    }
}

extern "C" void kernel_launch(void* const* d_in, const int* in_sizes, int n_in,
                              void* d_out, int out_size, void* d_ws, size_t ws_size,
                              hipStream_t stream) {
    (void)in_sizes; (void)n_in; (void)out_size;
    const float* xyz1 = (const float*)d_in[0];
    const float* xyz2 = (const float*)d_in[1];
    const float* p1   = (const float*)d_in[2];
    const float* p2   = (const float*)d_in[3];
    const float* W1   = (const float*)d_in[4];
    const float* b1   = (const float*)d_in[5];
    const float* W2   = (const float*)d_in[6];
    const float* b2   = (const float*)d_in[7];
    float* out = (float*)d_out;

    dim3 grid(BBATCH * (NPTS / TN));   // 1024 blocks
    dim3 block(256);
    _Float16* ws = (_Float16*)d_ws;
    const int nswz = NFRAG_P2 + NFRAG_W1 + NFRAG_W2;   // 540672 = 2112 * 256

    if (ws_size >= WS_F16_SPLIT * 2) {
        // split path: pre-swizzle everything, interp kernel, MLP kernel
        cvt_swz<<<dim3(nswz / 256), dim3(256), 0, stream>>>(p2, W1, W2, ws);
        cvt_p1 <<<dim3(4096),       dim3(256), 0, stream>>>(p1, ws + WS_XS);
        interp_k<<<grid, block, 0, stream>>>(xyz1, xyz2, ws + WS_P2S, ws + WS_XS);
        mlp_k   <<<grid, block, 0, stream>>>(ws + WS_W1S, b1, ws + WS_W2S, b2,
                                             ws + WS_XS, out);
    } else if (ws_size >= (size_t)WS_F16_FUSED * 2) {
        cvt_swz<<<dim3(nswz / 256), dim3(256), 0, stream>>>(p2, W1, W2, ws);
        fp_mfma6<true><<<grid, block, 0, stream>>>(xyz1, xyz2, p1, p2, W1, b1, W2, b2,
                                                   ws + WS_P2S, ws + WS_W1S, ws + WS_W2S, out);
    } else {
        fp_mfma6<false><<<grid, block, 0, stream>>>(xyz1, xyz2, p1, p2, W1, b1, W2, b2,
                                                    nullptr, nullptr, nullptr, out);
    }
}

// Round 9
// 171.805 us; speedup vs baseline: 1.3217x; 1.3217x over previous
//
#include <hip/hip_runtime.h>
#include <math.h>

// Problem constants (from reference setup_inputs)
#define BBATCH 16
#define NPTS   4096
#define MPTS   1024
#define C1c    128
#define C2c    256
#define CINc   384
#define H1c    256
#define H2c    128
#define TN     64

typedef _Float16 f16x8 __attribute__((ext_vector_type(8)));
typedef _Float16 f16x4 __attribute__((ext_vector_type(4)));
typedef float    f32x4 __attribute__((ext_vector_type(4)));

#define LDIW 136   // f16 stride, s_inv rows [64 n][128 m] (272 B rows)
#define LDXc 408   // f16 stride, s_X rows [64 n][384 k]
#define LDH  264   // f16 stride, s_H rows [64 n][256 k]

// shared memory union (bytes)
#define OFF_XYZ2  0                    // 12288 B [1024][3] f32          (phase A)
#define OFF_INV   12288                // 2 x 64*LDIW*2 = 34816 B        (phase A dbuf)
#define OFF_RED   47104                // 1024 B s_red[256]
#define OFF_RECIP 52224                // 256 B s_recip (beyond s_X: survives overlay)
#define SMEM_BYTES 52480               // s_X 52224 dominates; 3 blocks/CU

// ---- fragment-swizzled workspace layout (f16 elements) ----
//   p2s: frag ((b*32+s)*16 + wt)*64 + lane : (c=wt*16+(lane&15), m=s*32+(lane>>4)*8+i)
//   W1s: frag (wt*12 + kc)*64 + lane       : (o=wt*16+(lane&15), k=kc*32+(lane>>4)*8+i)
//   W2s: frag (wt2*8 + oc)*64 + lane       : (o=wt2*16+(lane&15), k=oc*32+(lane>>4)*8+i)
#define NFRAG_P2  (BBATCH * 32 * 16 * 64)        // 524288
#define NFRAG_W1  (16 * 12 * 64)                 // 12288
#define NFRAG_W2  (8 * 8 * 64)                   // 4096
#define WS_P2S  0
#define WS_W1S  (NFRAG_P2 * 8)                   // 4194304
#define WS_W2S  (WS_W1S + NFRAG_W1 * 8)
#define WS_F16_TOTAL (WS_W2S + NFRAG_W2 * 8)     // 4325376 f16 = 8650752 B

// ---------------------------------------------------------------------------
// pre-pass: convert + swizzle p2 / W1 / W2 into fragment-contiguous f16
__global__ __launch_bounds__(256) void cvt_swz(
    const float* __restrict__ p2, const float* __restrict__ W1,
    const float* __restrict__ W2, _Float16* __restrict__ ws)
{
    const int t = blockIdx.x * 256 + threadIdx.x;   // one fragment (8 f16) per thread
    const float* src;
    _Float16* dst;
    if (t < NFRAG_P2) {
        const int lane = t & 63, wt = (t >> 6) & 15, s = (t >> 10) & 31, b = t >> 15;
        const int c = wt * 16 + (lane & 15);
        const int m = s * 32 + (lane >> 4) * 8;
        src = p2 + ((size_t)(b * C2c + c)) * MPTS + m;
        dst = ws + WS_P2S + (size_t)t * 8;
    } else if (t < NFRAG_P2 + NFRAG_W1) {
        const int u = t - NFRAG_P2;
        const int lane = u & 63, kc = (u >> 6) % 12, wt = (u >> 6) / 12;
        const int o = wt * 16 + (lane & 15);
        const int k = kc * 32 + (lane >> 4) * 8;
        src = W1 + (size_t)o * CINc + k;
        dst = ws + WS_W1S + (size_t)u * 8;
    } else {
        const int v = t - NFRAG_P2 - NFRAG_W1;
        const int lane = v & 63, oc = (v >> 6) & 7, wt2 = v >> 9;
        const int o = wt2 * 16 + (lane & 15);
        const int k = oc * 32 + (lane >> 4) * 8;
        src = W2 + (size_t)o * H1c + k;
        dst = ws + WS_W2S + (size_t)v * 8;
    }
    const float4 a0 = *(const float4*)(src);
    const float4 a1 = *(const float4*)(src + 4);
    f16x8 h;
    h[0] = (_Float16)a0.x; h[1] = (_Float16)a0.y; h[2] = (_Float16)a0.z; h[3] = (_Float16)a0.w;
    h[4] = (_Float16)a1.x; h[5] = (_Float16)a1.y; h[6] = (_Float16)a1.z; h[7] = (_Float16)a1.w;
    *(f16x8*)dst = h;
}

// ---------------------------------------------------------------------------
// Fused kernel, R7 dataflow with SUPER-STEPPED phase A:
//   8 super-steps of 128 m; inv for the whole super-chunk generated into a
//   17 KB LDS buffer (dbuf), ONE barrier per super-step (8 total vs R7's 34).
//   Inner 4 m-chunks run barrier-free: A = p2s frags (contiguous 1KB loads,
//   register dbuf one chunk ahead), B = ds_read from the super-chunk buffer.
// Phase B: h = relu(W1 @ concat(p1, U/S) + b1): A = W1s frags, B = s_X.
// Phase C: out = relu(W2 @ h + b2):             A = W2s frags, B = s_H.
template <bool F16P>
__global__ __launch_bounds__(256, 3) void fp_mfma7(
    const float* __restrict__ xyz1, const float* __restrict__ xyz2,
    const float* __restrict__ p1,   const float* __restrict__ p2,
    const float* __restrict__ W1,   const float* __restrict__ b1v,
    const float* __restrict__ W2,   const float* __restrict__ b2v,
    const _Float16* __restrict__ p2s, const _Float16* __restrict__ W1s,
    const _Float16* __restrict__ W2s,
    float* __restrict__ out)
{
    __shared__ __align__(16) char smem[SMEM_BYTES];
    float*    s_xyz2  = (float*)(smem + OFF_XYZ2);
    _Float16* s_inv   = (_Float16*)(smem + OFF_INV);
    float*    s_red   = (float*)(smem + OFF_RED);
    float*    s_recip = (float*)(smem + OFF_RECIP);
    _Float16* s_X     = (_Float16*)smem;
    _Float16* s_H     = (_Float16*)smem;

    const int tid  = threadIdx.x;
    const int w    = tid >> 6;    // wave 0..3: owns c-rows [w*64, +64) in phase A
    const int L    = tid & 63;
    const int quad = L >> 4;
    const int l16  = L & 15;

    // XCD swizzle: each XCD sees 2 batches -> p2s working set (1 MB) L2-resident
    const int id = blockIdx.x;
    const int b  = (id & 7) * 2 + ((id >> 3) & 1);
    const int n0 = (id >> 4) * TN;

    const float* __restrict__ z2b = xyz2 + (size_t)b * MPTS * 3;
    const float* __restrict__ p2b = p2   + (size_t)b * C2c * MPTS;
    const _Float16* __restrict__ p2sb =
        F16P ? (p2s + (((size_t)b * 32 * 16 + (size_t)w * 4) * 64 + L) * 8) : (const _Float16*)nullptr;

    // stage xyz2 (12 KB)
    for (int i = tid; i < MPTS * 3 / 4; i += 256)
        ((f32x4*)s_xyz2)[i] = ((const f32x4*)z2b)[i];

    // inv-gen: thread owns query n = L, m-slice [ss*128 + w*32, +32)
    const float x1x = xyz1[((size_t)b * NPTS + n0 + L) * 3 + 0];
    const float x1y = xyz1[((size_t)b * NPTS + n0 + L) * 3 + 1];
    const float x1z = xyz1[((size_t)b * NPTS + n0 + L) * 3 + 2];

    f32x4 acc[4][4];   // [ct][nt]: row c = w*64+ct*16+quad*4+r, col n = nt*16+l16
    #pragma unroll
    for (int ct = 0; ct < 4; ++ct)
        #pragma unroll
        for (int nt = 0; nt < 4; ++nt)
            acc[ct][nt] = (f32x4){0.f, 0.f, 0.f, 0.f};

    float ssum = 0.f;
    f16x8 Aa[2][4];    // A-frag register dbuf, parity = chunk index & 1

    auto loadA = [&](int s, f16x8 dst[4]) {
        if (F16P) {
            const _Float16* ap = p2sb + (size_t)s * (16 * 64 * 8);
            #pragma unroll
            for (int ct = 0; ct < 4; ++ct)
                dst[ct] = *(const f16x8*)(ap + (size_t)ct * (64 * 8));
        } else {
            const float* ap = p2b + (size_t)(w * 64 + l16) * MPTS + s * 32 + quad * 8;
            #pragma unroll
            for (int ct = 0; ct < 4; ++ct) {
                const float4 a0 = *(const float4*)(ap + (size_t)ct * (16 * MPTS));
                const float4 a1 = *(const float4*)(ap + (size_t)ct * (16 * MPTS) + 4);
                f16x8 h;
                h[0] = (_Float16)a0.x; h[1] = (_Float16)a0.y; h[2] = (_Float16)a0.z; h[3] = (_Float16)a0.w;
                h[4] = (_Float16)a1.x; h[5] = (_Float16)a1.y; h[6] = (_Float16)a1.z; h[7] = (_Float16)a1.w;
                dst[ct] = h;
            }
        }
    };

    // generate the 128-m super-chunk ss into buffer ss&1 (32 rsq / thread)
    auto gen = [&](int ss_) {
        _Float16* buf = s_inv + (ss_ & 1) * (64 * LDIW);
        #pragma unroll
        for (int g = 0; g < 4; ++g) {
            const float* zp = s_xyz2 + (size_t)(ss_ * 128 + w * 32 + g * 8) * 3;  // wave-uniform
            f32x4 zr[6];
            #pragma unroll
            for (int j = 0; j < 6; ++j) zr[j] = ((const f32x4*)zp)[j];
            const float* zv = (const float*)zr;
            f16x8 iv;
            #pragma unroll
            for (int i = 0; i < 8; ++i) {
                const float dx = x1x - zv[3 * i + 0];
                const float dy = x1y - zv[3 * i + 1];
                const float dz = x1z - zv[3 * i + 2];
                const float d2 = fmaf(dx, dx, fmaf(dy, dy, fmaf(dz, dz, 1e-12f)));
                const float inv = __builtin_amdgcn_rsqf(d2);
                ssum += inv;
                iv[i] = (_Float16)inv;
            }
            *(f16x8*)(buf + L * LDIW + w * 32 + g * 8) = iv;
        }
    };

    __syncthreads();   // xyz2 staged
    loadA(0, Aa[0]);
    gen(0);
    __syncthreads();   // super-chunk 0 visible

    for (int ss = 0; ss < 8; ++ss) {
        if (ss + 1 < 8) gen(ss + 1);   // fills other buffer; overlaps inner MFMAs
        const _Float16* buf = s_inv + (ss & 1) * (64 * LDIW);
        #pragma unroll
        for (int cc = 0; cc < 4; ++cc) {
            const int s = ss * 4 + cc;
            if (s + 1 < 32) loadA(s + 1, Aa[(cc + 1) & 1]);   // barrier-free prefetch
            const _Float16* bb = buf + l16 * LDIW + cc * 32 + quad * 8;
            #pragma unroll
            for (int nt = 0; nt < 4; ++nt) {
                const f16x8 bf = *(const f16x8*)(bb + nt * (16 * LDIW));
                #pragma unroll
                for (int ct = 0; ct < 4; ++ct)
                    acc[ct][nt] = __builtin_amdgcn_mfma_f32_16x16x32_f16(Aa[cc & 1][ct], bf, acc[ct][nt], 0, 0, 0);
            }
        }
        __syncthreads();   // reads of buf(ss) done; writes of buf(ss+1) done
    }

    // ---- S[n] reduction over the 4 m-slice partials ----
    s_red[tid] = ssum;
    __syncthreads();
    if (tid < 64)
        s_recip[tid] = 1.0f / (s_red[tid] + s_red[tid + 64] + s_red[tid + 128] + s_red[tid + 192]);
    __syncthreads();   // s_recip ready; phase-A scratch dead -> s_X overlay safe

    // interp -> s_X[n][128 + c]
    {
        float rn4[4];
        #pragma unroll
        for (int nt = 0; nt < 4; ++nt) rn4[nt] = s_recip[nt * 16 + l16];
        #pragma unroll
        for (int ct = 0; ct < 4; ++ct)
            #pragma unroll
            for (int nt = 0; nt < 4; ++nt) {
                const f32x4 v = acc[ct][nt];
                const float r = rn4[nt];
                f16x4 hv;
                hv[0] = (_Float16)(v[0] * r);
                hv[1] = (_Float16)(v[1] * r);
                hv[2] = (_Float16)(v[2] * r);
                hv[3] = (_Float16)(v[3] * r);
                *(f16x4*)(&s_X[(nt * 16 + l16) * LDXc + 128 + w * 64 + ct * 16 + quad * 4]) = hv;
            }
    }
    // p1 -> s_X[n][c], c in [0,128)
    {
        const float* p1b = p1 + (size_t)b * C1c * NPTS + n0;
        #pragma unroll
        for (int cc = 0; cc < 8; ++cc) {
            const int c = w * 32 + cc * 4;
            f16x4 v;
            v[0] = (_Float16)p1b[(size_t)(c + 0) * NPTS + L];
            v[1] = (_Float16)p1b[(size_t)(c + 1) * NPTS + L];
            v[2] = (_Float16)p1b[(size_t)(c + 2) * NPTS + L];
            v[3] = (_Float16)p1b[(size_t)(c + 3) * NPTS + L];
            *(f16x4*)(&s_X[L * LDXc + c]) = v;
        }
    }
    __syncthreads();   // x matrix complete

    // ---------------- Phase B: h = relu(W1 @ x + b1), K=384 ----------------
    f32x4 hacc[4][4];
    #pragma unroll
    for (int ct = 0; ct < 4; ++ct)
        #pragma unroll
        for (int nt = 0; nt < 4; ++nt)
            hacc[ct][nt] = (f32x4){0.f, 0.f, 0.f, 0.f};

    #pragma unroll 2
    for (int kc = 0; kc < 12; ++kc) {
        f16x8 af[4];
        if (F16P) {
            const _Float16* wp = W1s + (((size_t)(w * 4) * 12 + kc) * 64 + L) * 8;
            #pragma unroll
            for (int ct = 0; ct < 4; ++ct)
                af[ct] = *(const f16x8*)(wp + (size_t)ct * (12 * 64 * 8));
        } else {
            const float* wp = W1 + (size_t)(w * 64 + l16) * CINc + kc * 32 + quad * 8;
            #pragma unroll
            for (int ct = 0; ct < 4; ++ct) {
                const float4 a0 = *(const float4*)(wp + ct * (16 * CINc));
                const float4 a1 = *(const float4*)(wp + ct * (16 * CINc) + 4);
                f16x8 h;
                h[0] = (_Float16)a0.x; h[1] = (_Float16)a0.y; h[2] = (_Float16)a0.z; h[3] = (_Float16)a0.w;
                h[4] = (_Float16)a1.x; h[5] = (_Float16)a1.y; h[6] = (_Float16)a1.z; h[7] = (_Float16)a1.w;
                af[ct] = h;
            }
        }
        #pragma unroll
        for (int nt = 0; nt < 4; ++nt) {
            const f16x8 bf = *(const f16x8*)(&s_X[(nt * 16 + l16) * LDXc + kc * 32 + quad * 8]);
            #pragma unroll
            for (int ct = 0; ct < 4; ++ct)
                hacc[ct][nt] = __builtin_amdgcn_mfma_f32_16x16x32_f16(af[ct], bf, hacc[ct][nt], 0, 0, 0);
        }
    }

    __syncthreads();   // all s_X reads done before overlaying s_H

    // bias + relu + stage h -> s_H[n][o1]
    {
        f32x4 bb[4];
        #pragma unroll
        for (int ct = 0; ct < 4; ++ct)
            bb[ct] = *(const f32x4*)(b1v + w * 64 + ct * 16 + quad * 4);
        #pragma unroll
        for (int ct = 0; ct < 4; ++ct)
            #pragma unroll
            for (int nt = 0; nt < 4; ++nt) {
                const f32x4 v = hacc[ct][nt];
                f16x4 hv;
                hv[0] = (_Float16)fmaxf(v[0] + bb[ct][0], 0.f);
                hv[1] = (_Float16)fmaxf(v[1] + bb[ct][1], 0.f);
                hv[2] = (_Float16)fmaxf(v[2] + bb[ct][2], 0.f);
                hv[3] = (_Float16)fmaxf(v[3] + bb[ct][3], 0.f);
                *(f16x4*)(&s_H[(nt * 16 + l16) * LDH + w * 64 + ct * 16 + quad * 4]) = hv;
            }
    }
    __syncthreads();

    // ---------------- Phase C: out = relu(W2 @ h + b2), K=256 ----------------
    f32x4 oacc[2][4];
    #pragma unroll
    for (int ct = 0; ct < 2; ++ct)
        #pragma unroll
        for (int nt = 0; nt < 4; ++nt)
            oacc[ct][nt] = (f32x4){0.f, 0.f, 0.f, 0.f};

    #pragma unroll 2
    for (int oc = 0; oc < 8; ++oc) {
        f16x8 af2[2];
        if (F16P) {
            const _Float16* wp = W2s + (((size_t)(w * 2) * 8 + oc) * 64 + L) * 8;
            #pragma unroll
            for (int ct = 0; ct < 2; ++ct)
                af2[ct] = *(const f16x8*)(wp + (size_t)ct * (8 * 64 * 8));
        } else {
            const float* wp = W2 + (size_t)(w * 32 + l16) * H1c + oc * 32 + quad * 8;
            #pragma unroll
            for (int ct = 0; ct < 2; ++ct) {
                const float4 a0 = *(const float4*)(wp + ct * (16 * H1c));
                const float4 a1 = *(const float4*)(wp + ct * (16 * H1c) + 4);
                f16x8 h;
                h[0] = (_Float16)a0.x; h[1] = (_Float16)a0.y; h[2] = (_Float16)a0.z; h[3] = (_Float16)a0.w;
                h[4] = (_Float16)a1.x; h[5] = (_Float16)a1.y; h[6] = (_Float16)a1.z; h[7] = (_Float16)a1.w;
                af2[ct] = h;
            }
        }
        #pragma unroll
        for (int nt = 0; nt < 4; ++nt) {
            const f16x8 bf = *(const f16x8*)(&s_H[(nt * 16 + l16) * LDH + oc * 32 + quad * 8]);
            #pragma unroll
            for (int ct = 0; ct < 2; ++ct)
                oacc[ct][nt] = __builtin_amdgcn_mfma_f32_16x16x32_f16(af2[ct], bf, oacc[ct][nt], 0, 0, 0);
        }
    }

    // epilogue: bias + relu + store
    {
        f32x4 bb2[2];
        #pragma unroll
        for (int ct = 0; ct < 2; ++ct)
            bb2[ct] = *(const f32x4*)(b2v + w * 32 + ct * 16 + quad * 4);
        #pragma unroll
        for (int ct = 0; ct < 2; ++ct)
            #pragma unroll
            for (int nt = 0; nt < 4; ++nt) {
                float* op = out + ((size_t)b * H2c + w * 32 + ct * 16 + quad * 4) * NPTS
                                + n0 + nt * 16 + l16;
                #pragma unroll
                for (int j = 0; j < 4; ++j)
                    op[(size_t)j * NPTS] = fmaxf(oacc[ct][nt][j] + bb2[ct][j], 0.f);
            }
    }
}

extern "C" void kernel_launch(void* const* d_in, const int* in_sizes, int n_in,
                              void* d_out, int out_size, void* d_ws, size_t ws_size,
                              hipStream_t stream) {
    (void)in_sizes; (void)n_in; (void)out_size;
    const float* xyz1 = (const float*)d_in[0];
    const float* xyz2 = (const float*)d_in[1];
    const float* p1   = (const float*)d_in[2];
    const float* p2   = (const float*)d_in[3];
    const float* W1   = (const float*)d_in[4];
    const float* b1   = (const float*)d_in[5];
    const float* W2   = (const float*)d_in[6];
    const float* b2   = (const float*)d_in[7];
    float* out = (float*)d_out;

    dim3 grid(BBATCH * (NPTS / TN));   // 1024 blocks
    dim3 block(256);
    if (ws_size >= (size_t)WS_F16_TOTAL * 2) {
        _Float16* ws = (_Float16*)d_ws;
        const int nswz = NFRAG_P2 + NFRAG_W1 + NFRAG_W2;   // 540672 = 2112 * 256
        cvt_swz<<<dim3(nswz / 256), dim3(256), 0, stream>>>(p2, W1, W2, ws);
        fp_mfma7<true><<<grid, block, 0, stream>>>(xyz1, xyz2, p1, p2, W1, b1, W2, b2,
                                                   ws + WS_P2S, ws + WS_W1S, ws + WS_W2S, out);
    } else {
        fp_mfma7<false><<<grid, block, 0, stream>>>(xyz1, xyz2, p1, p2, W1, b1, W2, b2,
                                                    nullptr, nullptr, nullptr, out);
    }
}